// Round 2
// baseline (301.397 us; speedup 1.0000x reference)
//
#include <hip/hip_runtime.h>
#include <hip/hip_bf16.h>
#include <stdint.h>

#define T_TOK 4096
#define NEXP  8
#define HDIM  1024
#define IDIM  2048
#define TOPK  2

typedef __attribute__((ext_vector_type(8))) short short8;
typedef __attribute__((ext_vector_type(4))) float f32x4;

__device__ __forceinline__ unsigned short f2bf(float f) {
    union { float f; unsigned int u; } v; v.f = f;
    unsigned int u = v.u;
    return (unsigned short)((u + 0x7fffu + ((u >> 16) & 1u)) >> 16);
}
__device__ __forceinline__ float bf2f(unsigned short s) {
    union { unsigned int u; float f; } v; v.u = ((unsigned int)s) << 16;
    return v.f;
}
__device__ __forceinline__ void gload_lds16(const void* g, void* l) {
    __builtin_amdgcn_global_load_lds(
        (const __attribute__((address_space(1))) unsigned int*)g,
        (__attribute__((address_space(3))) unsigned int*)l,
        16, 0, 0);
}

// ---------------- routing ----------------

__global__ void init_k(int* cnt) {
    if (threadIdx.x < NEXP) cnt[threadIdx.x] = 0;
}

__global__ void router_k(const float* __restrict__ logits, int* __restrict__ cnt,
                         int* __restrict__ eids, float* __restrict__ ews) {
    int t = blockIdx.x * blockDim.x + threadIdx.x;
    if (t >= T_TOK) return;
    const float4* lp = (const float4*)(logits + (size_t)t * NEXP);
    float4 a = lp[0], b = lp[1];
    float l[NEXP] = {a.x, a.y, a.z, a.w, b.x, b.y, b.z, b.w};
    int e0 = 0; float b0 = l[0];
    #pragma unroll
    for (int e = 1; e < NEXP; ++e) if (l[e] > b0) { b0 = l[e]; e0 = e; }
    int e1 = -1; float b1 = -1e30f;
    #pragma unroll
    for (int e = 0; e < NEXP; ++e) { if (e == e0) continue; if (l[e] > b1) { b1 = l[e]; e1 = e; } }
    float tt = __expf(b1 - b0);
    float w0 = 1.0f / (1.0f + tt);
    float w1 = 1.0f - w0;
    eids[2 * t] = e0; eids[2 * t + 1] = e1;
    ews[2 * t] = w0;  ews[2 * t + 1] = w1;
    atomicAdd(&cnt[e0], 1); atomicAdd(&cnt[e1], 1);
}

__global__ void offs_k(const int* __restrict__ cnt, int* __restrict__ offs, int* __restrict__ cursor) {
    if (threadIdx.x == 0) {
        int s = 0;
        for (int e = 0; e < NEXP; ++e) { offs[e] = s; cursor[e] = s; s += cnt[e]; }
        offs[NEXP] = s;
    }
}

__global__ void scatter_k(const int* __restrict__ eids, const float* __restrict__ ews,
                          int* __restrict__ cursor, int* __restrict__ tokid,
                          float* __restrict__ tokw, int* __restrict__ pos) {
    int t = blockIdx.x * blockDim.x + threadIdx.x;
    if (t >= T_TOK) return;
    #pragma unroll
    for (int k = 0; k < TOPK; ++k) {
        int e = eids[2 * t + k];
        int p = atomicAdd(&cursor[e], 1);
        tokid[p] = t; tokw[p] = ews[2 * t + k]; pos[2 * t + k] = p;
    }
}

// ---------------- fp32 -> bf16 convert (all three arrays, one kernel) ----------------

__global__ void cvt_all_k(const float* __restrict__ x, const float* __restrict__ w13,
                          const float* __restrict__ w2, unsigned short* __restrict__ xb,
                          unsigned short* __restrict__ w13b, unsigned short* __restrict__ w2b) {
    const int n0 = T_TOK * HDIM / 8;
    const int n1 = NEXP * 2 * IDIM * HDIM / 8;
    const int n2 = NEXP * HDIM * IDIM / 8;
    const int total = n0 + n1 + n2;
    for (int i = blockIdx.x * blockDim.x + threadIdx.x; i < total; i += gridDim.x * blockDim.x) {
        const float* s; unsigned short* d; int j;
        if (i < n0) { s = x; d = xb; j = i; }
        else if (i < n0 + n1) { s = w13; d = w13b; j = i - n0; }
        else { s = w2; d = w2b; j = i - n0 - n1; }
        const float4* p = (const float4*)(s + (size_t)j * 8);
        float4 a = p[0], b = p[1];
        union { unsigned short us[8]; short8 v; } r;
        r.us[0] = f2bf(a.x); r.us[1] = f2bf(a.y); r.us[2] = f2bf(a.z); r.us[3] = f2bf(a.w);
        r.us[4] = f2bf(b.x); r.us[5] = f2bf(b.y); r.us[6] = f2bf(b.z); r.us[7] = f2bf(b.w);
        *(short8*)(d + (size_t)j * 8) = r.v;
    }
}

// ---------------- GEMM1: h = silu(x@W1^T) * (x@W3^T) ----------------
// tile: 256 tokens x 128 out-cols; B-tile = 128 gate rows + 128 up rows
// 512 threads / 8 waves (2m x 4n); dbuf pipeline, 128KB dynamic LDS
// grid (IDIM/128=16, 16, NEXP)

__global__ __launch_bounds__(512, 2) void gemm1_k(
    const unsigned short* __restrict__ xb, const unsigned short* __restrict__ w13b,
    const int* __restrict__ tokid, const int* __restrict__ offs,
    unsigned short* __restrict__ hbuf)
{
    extern __shared__ unsigned short lds[];   // 2 buffers x 512 rows x 64 cols
    const int e = blockIdx.z;
    const int off_e = offs[e];
    const int cnt_e = offs[e + 1] - off_e;
    const int mt = blockIdx.y;
    if (mt * 256 >= cnt_e) return;
    const int nt = blockIdx.x;

    const int tid = threadIdx.x;
    const int w = tid >> 6, lane = tid & 63;
    const int ln15 = lane & 15, l16 = lane >> 4;
    const int wm = w >> 2, wn = w & 3;

    // staging sources: 8 x 16B chunks per thread per k-tile; LDS linear, source pre-swizzled
    const char* src[8];
    #pragma unroll
    for (int j = 0; j < 8; ++j) {
        int S = j * 512 + tid;
        int row = S >> 3;
        int ko = (S & 7) ^ (row & 7);
        if (row < 256) {
            int tr = mt * 256 + row;
            if (tr >= cnt_e) tr = cnt_e - 1;
            src[j] = (const char*)(xb + (size_t)tokid[off_e + tr] * HDIM + ko * 8);
        } else {
            int br = row - 256;
            int gr = (br < 128) ? (nt * 128 + br) : (IDIM + nt * 128 + (br - 128));
            src[j] = (const char*)(w13b + (size_t)e * (2 * IDIM * HDIM) + (size_t)gr * HDIM + ko * 8);
        }
    }
    int dst[8];
    #pragma unroll
    for (int j = 0; j < 8; ++j) dst[j] = (j * 512 + w * 64) * 8;

    const f32x4 z4 = {0.f, 0.f, 0.f, 0.f};
    f32x4 accg[8][2], accu[8][2];
    #pragma unroll
    for (int m = 0; m < 8; ++m)
        #pragma unroll
        for (int n = 0; n < 2; ++n) { accg[m][n] = z4; accu[m][n] = z4; }

    // prologue: stage tile 0 into buf0
    #pragma unroll
    for (int j = 0; j < 8; ++j) gload_lds16(src[j], &lds[dst[j]]);
    asm volatile("s_waitcnt vmcnt(0)" ::: "memory");
    __builtin_amdgcn_s_barrier();

    const int abase = (wm * 128 + ln15) * 64;
    const int gbase = (256 + wn * 32 + ln15) * 64;
    const int ubase = (384 + wn * 32 + ln15) * 64;
    const int s0 = (l16 ^ (ln15 & 7)) * 8;
    const int s1 = ((4 + l16) ^ (ln15 & 7)) * 8;

    #pragma unroll 2
    for (int kt = 0; kt < 16; ++kt) {
        const unsigned short* buf = lds + (kt & 1) * 32768;
        unsigned short* bufn = lds + ((kt & 1) ^ 1) * 32768;
        const int ktn = (kt < 15) ? (kt + 1) : 15;
        short8 a[8], bg[2], bu[2];
        // kk0 frag reads (all ds_reads precede any gload_lds this iter)
        #pragma unroll
        for (int m = 0; m < 8; ++m) a[m] = *(const short8*)&buf[abase + m * 1024 + s0];
        #pragma unroll
        for (int n = 0; n < 2; ++n) {
            bg[n] = *(const short8*)&buf[gbase + n * 1024 + s0];
            bu[n] = *(const short8*)&buf[ubase + n * 1024 + s0];
        }
        __builtin_amdgcn_sched_barrier(0);
        __builtin_amdgcn_s_setprio(1);
        #pragma unroll
        for (int m = 0; m < 8; ++m)
            #pragma unroll
            for (int n = 0; n < 2; ++n) {
                accg[m][n] = __builtin_amdgcn_mfma_f32_16x16x32_bf16(a[m], bg[n], accg[m][n], 0, 0, 0);
                accu[m][n] = __builtin_amdgcn_mfma_f32_16x16x32_bf16(a[m], bu[n], accu[m][n], 0, 0, 0);
            }
        __builtin_amdgcn_s_setprio(0);
        __builtin_amdgcn_sched_barrier(0);
        // kk1 frag reads
        #pragma unroll
        for (int m = 0; m < 8; ++m) a[m] = *(const short8*)&buf[abase + m * 1024 + s1];
        #pragma unroll
        for (int n = 0; n < 2; ++n) {
            bg[n] = *(const short8*)&buf[gbase + n * 1024 + s1];
            bu[n] = *(const short8*)&buf[ubase + n * 1024 + s1];
        }
        __builtin_amdgcn_sched_barrier(0);
        // prefetch next k-tile into other buffer; overlaps kk1 MFMA cluster
        #pragma unroll
        for (int j = 0; j < 8; ++j) gload_lds16(src[j] + (size_t)ktn * 128, &bufn[dst[j]]);
        __builtin_amdgcn_sched_barrier(0);
        __builtin_amdgcn_s_setprio(1);
        #pragma unroll
        for (int m = 0; m < 8; ++m)
            #pragma unroll
            for (int n = 0; n < 2; ++n) {
                accg[m][n] = __builtin_amdgcn_mfma_f32_16x16x32_bf16(a[m], bg[n], accg[m][n], 0, 0, 0);
                accu[m][n] = __builtin_amdgcn_mfma_f32_16x16x32_bf16(a[m], bu[n], accu[m][n], 0, 0, 0);
            }
        __builtin_amdgcn_s_setprio(0);
        asm volatile("s_waitcnt vmcnt(0)" ::: "memory");
        __builtin_amdgcn_s_barrier();
    }

    // epilogue: silu(gate)*up -> bf16 (wave-local: gate and up both in-reg)
    #pragma unroll
    for (int m = 0; m < 8; ++m) {
        #pragma unroll
        for (int i = 0; i < 4; ++i) {
            int r = mt * 256 + wm * 128 + m * 16 + l16 * 4 + i;
            if (r >= cnt_e) continue;
            size_t rb = (size_t)(off_e + r) * IDIM;
            #pragma unroll
            for (int n = 0; n < 2; ++n) {
                int col = nt * 128 + wn * 32 + n * 16 + ln15;
                float gv = accg[m][n][i], uv = accu[m][n][i];
                float hv = gv / (1.f + __expf(-gv)) * uv;
                hbuf[rb + col] = f2bf(hv);
            }
        }
    }
}

// ---------------- GEMM2: pb = bf16( tokw * (h @ W2^T) ) ----------------
// tile 256 x 128, 512 threads / 8 waves (4m x 2n), dbuf pipeline, 96KB LDS
// grid (HDIM/128=8, 16, NEXP)

__global__ __launch_bounds__(512, 2) void gemm2_k(
    const unsigned short* __restrict__ hbuf, const unsigned short* __restrict__ w2b,
    const int* __restrict__ offs, const float* __restrict__ tokw,
    unsigned short* __restrict__ pb)
{
    extern __shared__ unsigned short lds[];   // 2 buffers x 384 rows x 64 cols
    const int e = blockIdx.z;
    const int off_e = offs[e];
    const int cnt_e = offs[e + 1] - off_e;
    const int mt = blockIdx.y;
    if (mt * 256 >= cnt_e) return;
    const int nt = blockIdx.x;

    const int tid = threadIdx.x;
    const int w = tid >> 6, lane = tid & 63;
    const int ln15 = lane & 15, l16 = lane >> 4;
    const int wm = w >> 1, wn = w & 1;

    const char* src[6];
    #pragma unroll
    for (int j = 0; j < 6; ++j) {
        int S = j * 512 + tid;
        int row = S >> 3;
        int ko = (S & 7) ^ (row & 7);
        if (row < 256) {
            int tr = mt * 256 + row;
            if (tr >= cnt_e) tr = cnt_e - 1;
            src[j] = (const char*)(hbuf + (size_t)(off_e + tr) * IDIM + ko * 8);
        } else {
            int wr = nt * 128 + (row - 256);
            src[j] = (const char*)(w2b + (size_t)e * (HDIM * IDIM) + (size_t)wr * IDIM + ko * 8);
        }
    }
    int dst[6];
    #pragma unroll
    for (int j = 0; j < 6; ++j) dst[j] = (j * 512 + w * 64) * 8;

    const f32x4 z4 = {0.f, 0.f, 0.f, 0.f};
    f32x4 acc[4][4];
    #pragma unroll
    for (int m = 0; m < 4; ++m)
        #pragma unroll
        for (int n = 0; n < 4; ++n) acc[m][n] = z4;

    #pragma unroll
    for (int j = 0; j < 6; ++j) gload_lds16(src[j], &lds[dst[j]]);
    asm volatile("s_waitcnt vmcnt(0)" ::: "memory");
    __builtin_amdgcn_s_barrier();

    const int abase = (wm * 64 + ln15) * 64;
    const int bbase = (256 + wn * 64 + ln15) * 64;
    const int s0 = (l16 ^ (ln15 & 7)) * 8;
    const int s1 = ((4 + l16) ^ (ln15 & 7)) * 8;

    #pragma unroll 2
    for (int kt = 0; kt < 32; ++kt) {
        const unsigned short* buf = lds + (kt & 1) * 24576;
        unsigned short* bufn = lds + ((kt & 1) ^ 1) * 24576;
        const int ktn = (kt < 31) ? (kt + 1) : 31;
        short8 av[4], bv[4];
        #pragma unroll
        for (int m = 0; m < 4; ++m) av[m] = *(const short8*)&buf[abase + m * 1024 + s0];
        #pragma unroll
        for (int n = 0; n < 4; ++n) bv[n] = *(const short8*)&buf[bbase + n * 1024 + s0];
        __builtin_amdgcn_sched_barrier(0);
        __builtin_amdgcn_s_setprio(1);
        #pragma unroll
        for (int m = 0; m < 4; ++m)
            #pragma unroll
            for (int n = 0; n < 4; ++n)
                acc[m][n] = __builtin_amdgcn_mfma_f32_16x16x32_bf16(av[m], bv[n], acc[m][n], 0, 0, 0);
        __builtin_amdgcn_s_setprio(0);
        __builtin_amdgcn_sched_barrier(0);
        #pragma unroll
        for (int m = 0; m < 4; ++m) av[m] = *(const short8*)&buf[abase + m * 1024 + s1];
        #pragma unroll
        for (int n = 0; n < 4; ++n) bv[n] = *(const short8*)&buf[bbase + n * 1024 + s1];
        __builtin_amdgcn_sched_barrier(0);
        #pragma unroll
        for (int j = 0; j < 6; ++j) gload_lds16(src[j] + (size_t)ktn * 128, &bufn[dst[j]]);
        __builtin_amdgcn_sched_barrier(0);
        __builtin_amdgcn_s_setprio(1);
        #pragma unroll
        for (int m = 0; m < 4; ++m)
            #pragma unroll
            for (int n = 0; n < 4; ++n)
                acc[m][n] = __builtin_amdgcn_mfma_f32_16x16x32_bf16(av[m], bv[n], acc[m][n], 0, 0, 0);
        __builtin_amdgcn_s_setprio(0);
        asm volatile("s_waitcnt vmcnt(0)" ::: "memory");
        __builtin_amdgcn_s_barrier();
    }

    #pragma unroll
    for (int m = 0; m < 4; ++m) {
        #pragma unroll
        for (int i = 0; i < 4; ++i) {
            int r = mt * 256 + wm * 64 + m * 16 + l16 * 4 + i;
            if (r >= cnt_e) continue;
            float wgt = tokw[off_e + r];
            size_t rb = (size_t)(off_e + r) * HDIM;
            #pragma unroll
            for (int n = 0; n < 4; ++n) {
                int col = nt * 128 + wn * 64 + n * 16 + ln15;
                pb[rb + col] = f2bf(wgt * acc[m][n][i]);
            }
        }
    }
}

// ---------------- combine: out[t] = pb[p0] + pb[p1]  (weights pre-applied) ----------------

__global__ void combine2_k(const unsigned short* __restrict__ pb, const int* __restrict__ pos,
                           float* __restrict__ out) {
    int idx = blockIdx.x * blockDim.x + threadIdx.x;   // T*H/8 threads
    int t = idx >> 7, c8 = idx & 127;
    int p0 = pos[2 * t], p1 = pos[2 * t + 1];
    short8 a = *(const short8*)(pb + (size_t)p0 * HDIM + c8 * 8);
    short8 b = *(const short8*)(pb + (size_t)p1 * HDIM + c8 * 8);
    float4 o0, o1;
    o0.x = bf2f((unsigned short)a[0]) + bf2f((unsigned short)b[0]);
    o0.y = bf2f((unsigned short)a[1]) + bf2f((unsigned short)b[1]);
    o0.z = bf2f((unsigned short)a[2]) + bf2f((unsigned short)b[2]);
    o0.w = bf2f((unsigned short)a[3]) + bf2f((unsigned short)b[3]);
    o1.x = bf2f((unsigned short)a[4]) + bf2f((unsigned short)b[4]);
    o1.y = bf2f((unsigned short)a[5]) + bf2f((unsigned short)b[5]);
    o1.z = bf2f((unsigned short)a[6]) + bf2f((unsigned short)b[6]);
    o1.w = bf2f((unsigned short)a[7]) + bf2f((unsigned short)b[7]);
    float* op = out + (size_t)t * HDIM + c8 * 8;
    ((float4*)op)[0] = o0;
    ((float4*)op)[1] = o1;
}

// ---------------- launch ----------------

extern "C" void kernel_launch(void* const* d_in, const int* in_sizes, int n_in,
                              void* d_out, int out_size, void* d_ws, size_t ws_size,
                              hipStream_t stream) {
    const float* x      = (const float*)d_in[0];
    const float* logits = (const float*)d_in[1];
    const float* w13    = (const float*)d_in[2];
    const float* w2     = (const float*)d_in[3];
    float* out = (float*)d_out;

    char* ws = (char*)d_ws;
    size_t off = 0;
    auto carve = [&](size_t bytes) -> void* {
        void* p = ws + off;
        off = (off + bytes + 255) & ~(size_t)255;
        return p;
    };
    int*   cnt    = (int*)carve(NEXP * 4);
    int*   offs   = (int*)carve((NEXP + 1) * 4);
    int*   cursor = (int*)carve(NEXP * 4);
    int*   eids   = (int*)carve((size_t)T_TOK * 2 * 4);
    float* ews    = (float*)carve((size_t)T_TOK * 2 * 4);
    int*   tokid  = (int*)carve((size_t)(T_TOK * TOPK + 256) * 4);
    float* tokw   = (float*)carve((size_t)T_TOK * TOPK * 4);
    int*   pos    = (int*)carve((size_t)T_TOK * TOPK * 4);
    unsigned short* xb   = (unsigned short*)carve((size_t)T_TOK * HDIM * 2);
    unsigned short* w13b = (unsigned short*)carve((size_t)NEXP * 2 * IDIM * HDIM * 2);
    unsigned short* w2b  = (unsigned short*)carve((size_t)NEXP * HDIM * IDIM * 2);
    unsigned short* hbuf = (unsigned short*)carve((size_t)T_TOK * TOPK * IDIM * 2);
    unsigned short* pb   = (unsigned short*)carve((size_t)T_TOK * TOPK * HDIM * 2);

    hipFuncSetAttribute(reinterpret_cast<const void*>(gemm1_k),
                        hipFuncAttributeMaxDynamicSharedMemorySize, 131072);
    hipFuncSetAttribute(reinterpret_cast<const void*>(gemm2_k),
                        hipFuncAttributeMaxDynamicSharedMemorySize, 98304);

    init_k<<<1, 64, 0, stream>>>(cnt);
    router_k<<<T_TOK / 256, 256, 0, stream>>>(logits, cnt, eids, ews);
    offs_k<<<1, 1, 0, stream>>>(cnt, offs, cursor);
    scatter_k<<<T_TOK / 256, 256, 0, stream>>>(eids, ews, cursor, tokid, tokw, pos);

    cvt_all_k<<<4096, 256, 0, stream>>>(x, w13, w2, xb, w13b, w2b);

    gemm1_k<<<dim3(IDIM / 128, 16, NEXP), 512, 131072, stream>>>(xb, w13b, tokid, offs, hbuf);
    gemm2_k<<<dim3(HDIM / 128, 16, NEXP), 512, 98304, stream>>>(hbuf, w2b, offs, tokw, pb);

    combine2_k<<<(T_TOK * HDIM / 8) / 256, 256, 0, stream>>>(pb, pos, out);
}